// Round 13
// baseline (307.282 us; speedup 1.0000x reference)
//
#include <hip/hip_runtime.h>
#include <hip/hip_bf16.h>
#include <stdint.h>
#include <stddef.h>

typedef __attribute__((ext_vector_type(8))) short short8;
typedef __attribute__((ext_vector_type(4))) float f32x4;

#define MFMA16(a, b, c) __builtin_amdgcn_mfma_f32_16x16x32_bf16((a), (b), (c), 0, 0, 0)

// Q pre-scale: HEAD_DIM^-0.5 * log2(e); flash uses raw v_exp_f32 (exp2)
#define QSCALE 0.1803368801111204f

#if __has_builtin(__builtin_amdgcn_exp2f)
#define EXP2(x) __builtin_amdgcn_exp2f(x)
#else
#define EXP2(x) __builtin_exp2f(x)
#endif

__device__ __forceinline__ float b2f(short x) {
    unsigned u = ((unsigned)(unsigned short)x) << 16;
    float f; __builtin_memcpy(&f, &u, 4); return f;
}
// round-nearest-even f32->bf16 (scalar)
__device__ __forceinline__ short f2b(float f) {
    unsigned u; __builtin_memcpy(&u, &f, 4);
    u = (u + 0x7FFFu + ((u >> 16) & 1u)) >> 16;
    return (short)u;
}
// two f32 -> packed bf16x2 in 3 VALU (2 adds + v_perm), round-half-up.
// NOTE: __float22bfloat162_rn compiled to a multi-instr software sequence
// (r12: VALUBusy 54->67%) — do NOT use it in hot loops.
__device__ __forceinline__ unsigned pack2(float a, float b) {
    unsigned ua, ub; __builtin_memcpy(&ua, &a, 4); __builtin_memcpy(&ub, &b, 4);
    return __builtin_amdgcn_perm(ub + 0x8000u, ua + 0x8000u, 0x07060302u);
}
// 8 contiguous f32 -> bf16x8 (RNE)
__device__ __forceinline__ short8 load8f(const float* p) {
    const float4 f0 = *(const float4*)p;
    const float4 f1 = *(const float4*)(p + 4);
    short8 r;
    r[0]=f2b(f0.x); r[1]=f2b(f0.y); r[2]=f2b(f0.z); r[3]=f2b(f0.w);
    r[4]=f2b(f1.x); r[5]=f2b(f1.y); r[6]=f2b(f1.z); r[7]=f2b(f1.w);
    return r;
}

// ---------------------------------------------------------------------------
// Fused f32->bf16 converter for up to 3 arrays. nX = elems/8.
// ---------------------------------------------------------------------------
__global__ __launch_bounds__(256) void cvt3(
    const float* __restrict__ s0, short* __restrict__ d0, int n0,
    const float* __restrict__ s1, short* __restrict__ d1, int n1,
    const float* __restrict__ s2, short* __restrict__ d2, int n2)
{
    int i = blockIdx.x * 256 + threadIdx.x;
    if (i < n0) { *(short8*)(d0 + (size_t)i * 8) = load8f(s0 + (size_t)i * 8); return; }
    i -= n0;
    if (i < n1) { *(short8*)(d1 + (size_t)i * 8) = load8f(s1 + (size_t)i * 8); return; }
    i -= n1;
    if (i < n2) { *(short8*)(d2 + (size_t)i * 8) = load8f(s2 + (size_t)i * 8); }
}

// ---------------------------------------------------------------------------
// Fused QKV GEMM (bf16 in/out). Grid (64,12): sec = y>>2 (0=Q,1=K,2=V).
//   Q (x QSCALE) -> Qb[bh][seq][64];  K -> Kb[bh][seq][64]
//   V -> Vb[bh][64][seq] via LDS-transposed epilogue (coalesced b128 stores)
// ---------------------------------------------------------------------------
__global__ __launch_bounds__(256) void qkv_gemm(
    const short* __restrict__ X, const short* __restrict__ W,
    const float* __restrict__ bias,
    short* __restrict__ Qb, short* __restrict__ Kb, short* __restrict__ Vb)
{
    __shared__ short sT[128][132];

    const int tid  = threadIdx.x;
    const int wv   = tid >> 6;
    const int lane = tid & 63;
    const int l15  = lane & 15;
    const int quad = lane >> 4;
    const int m0   = blockIdx.x * 128 + (wv >> 1) * 64;
    const int sec  = blockIdx.y >> 2;
    const int bis  = blockIdx.y & 3;
    const int nbase = sec * 512 + bis * 128;
    const int j0   = (wv & 1) * 64;

    const f32x4 zero = {0.f, 0.f, 0.f, 0.f};
    f32x4 acc[4][4];
#pragma unroll
    for (int i = 0; i < 4; i++)
#pragma unroll
        for (int j = 0; j < 4; j++) acc[i][j] = zero;

    for (int k0 = 0; k0 < 512; k0 += 32) {
        short8 a[4], b[4];
#pragma unroll
        for (int i = 0; i < 4; i++)
            a[i] = *(const short8*)(X + (size_t)(m0 + i * 16 + l15) * 512 + k0 + quad * 8);
#pragma unroll
        for (int j = 0; j < 4; j++)
            b[j] = *(const short8*)(W + (size_t)(nbase + j0 + j * 16 + l15) * 512 + k0 + quad * 8);
#pragma unroll
        for (int i = 0; i < 4; i++)
#pragma unroll
            for (int j = 0; j < 4; j++)
                acc[i][j] = MFMA16(a[i], b[j], acc[i][j]);
    }

    if (sec < 2) {
        const float scale = (sec == 0) ? QSCALE : 1.0f;
        short* dst = (sec == 0) ? Qb : Kb;
#pragma unroll
        for (int j = 0; j < 4; j++) {
            const int jc = bis * 128 + j0 + j * 16 + l15;   // 0..511 in section
            const float bs = bias[sec * 512 + jc];
            const int hl = jc >> 6, d = jc & 63;
#pragma unroll
            for (int i = 0; i < 4; i++) {
#pragma unroll
                for (int r = 0; r < 4; r++) {
                    const int m = m0 + i * 16 + quad * 4 + r;
                    const int bb = m >> 12, seq = m & 4095;
                    dst[((size_t)(bb * 8 + hl) * 4096 + seq) * 64 + d] =
                        f2b((acc[i][j][r] + bs) * scale);
                }
            }
        }
    } else {
        // V: pack 4 consecutive seq into b64 LDS writes, then coalesced b128
#pragma unroll
        for (int j = 0; j < 4; j++) {
            const int jcl = j0 + j * 16 + l15;             // 0..127
            const float bs = bias[nbase + jcl];
#pragma unroll
            for (int i = 0; i < 4; i++) {
                uint2 w;
                w.x = pack2(acc[i][j][0] + bs, acc[i][j][1] + bs);
                w.y = pack2(acc[i][j][2] + bs, acc[i][j][3] + bs);
                *(uint2*)&sT[jcl][(wv >> 1) * 64 + i * 16 + quad * 4] = w;
            }
        }
        __syncthreads();

        const int jcl = tid >> 1, half = tid & 1;
        const int hl = (bis * 128 + jcl) >> 6;
        const int d  = jcl & 63;
        const int bb = (blockIdx.x * 128) >> 12;
        const int seq0 = ((blockIdx.x * 128) & 4095) + half * 64;
        short* dst = Vb + ((size_t)(bb * 8 + hl) * 64 + d) * 4096 + seq0;
#pragma unroll
        for (int u = 0; u < 8; u++)
            *(short8*)(dst + u * 8) = *(const short8*)&sT[jcl][half * 64 + u * 8];
    }
}

// ---------------------------------------------------------------------------
// Flash attention — round-10 compute structure (grid (32,16,2), 4-wave
// blocks, 2 query-groups/wave, K/V staged + register-prefetched) with:
//   * SINGLE wave-private sP buffer -> LDS 27648 B. Occupancy data
//     (r6/r8/r10/r12): 27.6 KB -> ~3.2 blocks/CU, 36.9 KB -> ~2.1. The
//     dbuf cost a resident block; groups serialize via 2 fences instead
//     (hidden at 12+ waves/CU — r11's regression was at 6 waves/CU).
//   * raw v_exp_f32 (EXP2; logits pre-scaled by log2e) — exp2f/OCML and
//     __float22bfloat162_rn are multi-instr (r12 VALUBusy 54->67%); pack
//     via the 3-VALU perm pack2 (r8-r10 proven, absmax 4.88e-4).
//   * row sums via ones-MFMA accumulated in C (VALU -> idle MFMA pipe).
// Split-K=2 partials (no-max streaming softmax): O = (l0*O0+l1*O1)/(l0+l1).
// ---------------------------------------------------------------------------
__global__ __launch_bounds__(256) void flash_attn(
    const short* __restrict__ Q, const short* __restrict__ K,
    const short* __restrict__ V, short* __restrict__ PO0,
    short* __restrict__ PO1, float* __restrict__ lbuf, int ktiles)
{
    __shared__ short sK[64][72];
    __shared__ short sV[64][72];          // sV[d][key]
    __shared__ short sP[4][16][72];       // single per-wave buffer (27.6 KB total)

    const int tid  = threadIdx.x;
    const int wv   = tid >> 6;
    const int lane = tid & 63;
    const int l15  = lane & 15;
    const int quad = lane >> 4;
    const int bh = blockIdx.y;
    const int b = bh >> 3, h = bh & 7;
    const int qw = blockIdx.x * 128 + wv * 32;   // wave's first query
    const int ks = blockIdx.z;
    const int key0 = ks * ktiles * 64;

    const short* Qb = Q + (size_t)bh * 4096 * 64;
    const short* Kb = K + (size_t)bh * 4096 * 64;
    const short* Vb = V + (size_t)bh * 64 * 4096;

    // Q fragments (B-operand): B[k=d][n=query l15]; Q pre-scaled by QSCALE
    const short8 aq00 = *(const short8*)(Qb + (size_t)(qw + l15) * 64 + quad * 8);
    const short8 aq01 = *(const short8*)(Qb + (size_t)(qw + l15) * 64 + 32 + quad * 8);
    const short8 aq10 = *(const short8*)(Qb + (size_t)(qw + 16 + l15) * 64 + quad * 8);
    const short8 aq11 = *(const short8*)(Qb + (size_t)(qw + 16 + l15) * 64 + 32 + quad * 8);

    const f32x4 zero = {0.f, 0.f, 0.f, 0.f};
    f32x4 o0[4], o1[4];
    f32x4 lac0 = zero, lac1 = zero;       // row sums via ones-MFMA
#pragma unroll
    for (int r = 0; r < 4; r++) { o0[r] = zero; o1[r] = zero; }
    const short one_bf = (short)0x3F80;
    const short8 ones = {one_bf, one_bf, one_bf, one_bf,
                         one_bf, one_bf, one_bf, one_bf};

    // staging: 1024 16B-chunks (K:512, V:512) over 256 threads -> 2+2 each
    int srow[2], scb[2];
#pragma unroll
    for (int i = 0; i < 2; i++) {
        const int c = tid + i * 256;
        srow[i] = c >> 3; scb[i] = (c & 7) * 8;
    }
    short8 pk[2], pv[2];
#pragma unroll
    for (int i = 0; i < 2; i++) {
        pk[i] = *(const short8*)(Kb + (size_t)(key0 + srow[i]) * 64 + scb[i]);
        pv[i] = *(const short8*)(Vb + (size_t)srow[i] * 4096 + key0 + scb[i]);
    }

    for (int kt = 0; kt < ktiles; ++kt) {
        const int k0 = key0 + kt * 64;
        __syncthreads();               // all waves done reading prev tile
#pragma unroll
        for (int i = 0; i < 2; i++) {
            *(short8*)&sK[srow[i]][scb[i]] = pk[i];
            *(short8*)&sV[srow[i]][scb[i]] = pv[i];
        }
        __syncthreads();               // staging visible

        if (kt + 1 < ktiles) {         // prefetch next tile (overlaps compute)
            const int k0n = k0 + 64;
#pragma unroll
            for (int i = 0; i < 2; i++) {
                pk[i] = *(const short8*)(Kb + (size_t)(k0n + srow[i]) * 64 + scb[i]);
                pv[i] = *(const short8*)(Vb + (size_t)srow[i] * 4096 + k0n + scb[i]);
            }
        }

        // S^T = K x Q^T for both groups (A=K[key][d] frags from LDS)
        f32x4 ST0[4], ST1[4];
#pragma unroll
        for (int c = 0; c < 4; c++) {
            const short8 bk0 = *(const short8*)&sK[c * 16 + l15][quad * 8];
            const short8 bk1 = *(const short8*)&sK[c * 16 + l15][32 + quad * 8];
            ST0[c] = MFMA16(bk1, aq01, MFMA16(bk0, aq00, zero));
            ST1[c] = MFMA16(bk1, aq11, MFMA16(bk0, aq10, zero));
        }

        // ---- group 0 through the single sP buffer ----
#pragma unroll
        for (int c = 0; c < 4; c++) {
            uint2 w;
            w.x = pack2(EXP2(ST0[c][0]), EXP2(ST0[c][1]));
            w.y = pack2(EXP2(ST0[c][2]), EXP2(ST0[c][3]));
            *(uint2*)&sP[wv][l15][c * 16 + quad * 4] = w;
        }
        __threadfence_block();         // g0 writes -> g0 reads
        {
            const short8 bp0 = *(const short8*)&sP[wv][l15][quad * 8];
            const short8 bp1 = *(const short8*)&sP[wv][l15][32 + quad * 8];
            lac0 = MFMA16(ones, bp0, lac0);
            lac0 = MFMA16(ones, bp1, lac0);
#pragma unroll
            for (int td = 0; td < 4; td++) {
                const short8 bv0 = *(const short8*)&sV[td * 16 + l15][quad * 8];
                const short8 bv1 = *(const short8*)&sV[td * 16 + l15][32 + quad * 8];
                o0[td] = MFMA16(bv0, bp0, o0[td]);
                o0[td] = MFMA16(bv1, bp1, o0[td]);
            }
        }
        __threadfence_block();         // g0 reads -> g1 writes

        // ---- group 1 ----
#pragma unroll
        for (int c = 0; c < 4; c++) {
            uint2 w;
            w.x = pack2(EXP2(ST1[c][0]), EXP2(ST1[c][1]));
            w.y = pack2(EXP2(ST1[c][2]), EXP2(ST1[c][3]));
            *(uint2*)&sP[wv][l15][c * 16 + quad * 4] = w;
        }
        __threadfence_block();         // g1 writes -> g1 reads
        {
            const short8 bp0 = *(const short8*)&sP[wv][l15][quad * 8];
            const short8 bp1 = *(const short8*)&sP[wv][l15][32 + quad * 8];
            lac1 = MFMA16(ones, bp0, lac1);
            lac1 = MFMA16(ones, bp1, lac1);
#pragma unroll
            for (int td = 0; td < 4; td++) {
                const short8 bv0 = *(const short8*)&sV[td * 16 + l15][quad * 8];
                const short8 bv1 = *(const short8*)&sV[td * 16 + l15][32 + quad * 8];
                o1[td] = MFMA16(bv0, bp0, o1[td]);
                o1[td] = MFMA16(bv1, bp1, o1[td]);
            }
        }
        // g1 reads -> next-tile g0 writes ordered by the staging barrier
    }

    const float l0 = lac0[0];              // every reg/quad holds the sum
    const float l1 = lac1[0];
    const float inv0 = 1.f / fmaxf(l0, 1e-30f);
    const float inv1 = 1.f / fmaxf(l1, 1e-30f);

    short* PO = (ks == 0) ? PO0 : PO1;
#pragma unroll
    for (int td = 0; td < 4; td++) {
        uint2 w0, w1;
        w0.x = pack2(o0[td][0] * inv0, o0[td][1] * inv0);
        w0.y = pack2(o0[td][2] * inv0, o0[td][3] * inv0);
        w1.x = pack2(o1[td][0] * inv1, o1[td][1] * inv1);
        w1.y = pack2(o1[td][2] * inv1, o1[td][3] * inv1);
        const int col = h * 64 + td * 16 + quad * 4;
        *(uint2*)(PO + ((size_t)b * 4096 + qw + l15) * 512 + col) = w0;
        *(uint2*)(PO + ((size_t)b * 4096 + qw + 16 + l15) * 512 + col) = w1;
    }
    if (quad == 0) {
        lbuf[((size_t)ks * 16 + bh) * 4096 + qw + l15] = l0;
        lbuf[((size_t)ks * 16 + bh) * 4096 + qw + 16 + l15] = l1;
    }
}

// ---------------------------------------------------------------------------
// Combine the 2 key-split partials (in-place over PO1 = attn region):
// attn = (l0*O0 + l1*O1) / (l0+l1). Element-wise, memory-bound.
// ---------------------------------------------------------------------------
__global__ __launch_bounds__(256) void combine(
    const short* __restrict__ PO0, short* __restrict__ PO1,
    const float* __restrict__ L)
{
    const int i = blockIdx.x * 256 + threadIdx.x;   // 0..524287
    const size_t flat = (size_t)i * 8;
    const int col = (int)(flat & 511);
    const int q   = (int)((flat >> 9) & 4095);
    const int b   = (int)(flat >> 21);
    const int bh  = b * 8 + (col >> 6);
    const float l0 = L[(size_t)bh * 4096 + q];
    const float l1 = L[(size_t)65536 + (size_t)bh * 4096 + q];
    const float inv = 1.f / (l0 + l1);
    const float w0 = l0 * inv, w1 = l1 * inv;
    const short8 a = *(const short8*)(PO0 + flat);
    const short8 c = *(const short8*)(PO1 + flat);
    short8 r;
#pragma unroll
    for (int k = 0; k < 8; k += 2) {
        const unsigned p = pack2(w0 * b2f(a[k]) + w1 * b2f(c[k]),
                                 w0 * b2f(a[k + 1]) + w1 * b2f(c[k + 1]));
        r[k]     = (short)(p & 0xFFFF);
        r[k + 1] = (short)(p >> 16);
    }
    *(short8*)(PO1 + flat) = r;
}

// ---------------------------------------------------------------------------
// Projection piece: dst[m_local][n] = attn[m_base+m_local] @ pw^T + proj_b.
// attn bf16, pw bf16, bias f32, dst f32. Grid (rows/128, 4).
// ---------------------------------------------------------------------------
__global__ __launch_bounds__(256) void proj_piece(
    const short* __restrict__ A, const short* __restrict__ W,
    const float* __restrict__ bias, float* __restrict__ dst, int m_base)
{
    const int tid  = threadIdx.x;
    const int wv   = tid >> 6;
    const int lane = tid & 63;
    const int l15  = lane & 15;
    const int quad = lane >> 4;
    const int m0 = blockIdx.x * 128 + (wv >> 1) * 64;
    const int n0 = blockIdx.y * 128 + (wv & 1) * 64;

    const f32x4 zero = {0.f, 0.f, 0.f, 0.f};
    f32x4 acc[4][4];
#pragma unroll
    for (int i = 0; i < 4; i++)
#pragma unroll
        for (int j = 0; j < 4; j++) acc[i][j] = zero;

    for (int k0 = 0; k0 < 512; k0 += 32) {
        short8 a[4], b[4];
#pragma unroll
        for (int i = 0; i < 4; i++)
            a[i] = *(const short8*)(A + (size_t)(m_base + m0 + i * 16 + l15) * 512 + k0 + quad * 8);
#pragma unroll
        for (int j = 0; j < 4; j++)
            b[j] = *(const short8*)(W + (size_t)(n0 + j * 16 + l15) * 512 + k0 + quad * 8);
#pragma unroll
        for (int i = 0; i < 4; i++)
#pragma unroll
            for (int j = 0; j < 4; j++)
                acc[i][j] = MFMA16(a[i], b[j], acc[i][j]);
    }

#pragma unroll
    for (int j = 0; j < 4; j++) {
        const int n = n0 + j * 16 + l15;
        const float bs = bias[n];
#pragma unroll
        for (int i = 0; i < 4; i++) {
#pragma unroll
            for (int r = 0; r < 4; r++) {
                const int m = m0 + i * 16 + quad * 4 + r;
                dst[(size_t)m * 512 + n] = acc[i][j][r] + bs;
            }
        }
    }
}

// ---------------------------------------------------------------------------
// Memory plan (ws >= 25 MB, proven):
//   d_out [0,8M):    xb -> PO0 (flash split 0) -> proj A output [0,8M)
//   d_out [8M,9.5M): wb (dead after qkv)
//   d_out [8M,16M):  PO1 (flash split 1) -> combine in-place -> attn
//   proj telescoping: A rows [0,4096) -> d_out [0,8M) direct (reads [8M,16M));
//   B rows [4096,6144) -> d_out [8M,12M) direct (reads attn [12M,14M) only —
//   disjoint; A already consumed [8M,12M)); C rows [6144,8192) -> 4 MB ws
//   stage (reads [14M,16M)) -> copy to [12M,16M).
//   ws [0,8M) Qf | [8M,16M) Kf | [16M,24M) Vf | [24M,24.5M) lbuf | pwb
// ---------------------------------------------------------------------------
extern "C" void kernel_launch(void* const* d_in, const int* in_sizes, int n_in,
                              void* d_out, int out_size, void* d_ws, size_t ws_size,
                              hipStream_t stream)
{
    const float* x      = (const float*)d_in[0];   // [2,4096,512] f32
    const float* qkv_w  = (const float*)d_in[1];   // [1536,512]   f32
    const float* qkv_b  = (const float*)d_in[2];   // [1536]       f32
    const float* proj_w = (const float*)d_in[3];   // [512,512]    f32
    const float* proj_b = (const float*)d_in[4];   // [512]        f32

    const size_t MB = 1024 * 1024;
    short* xb   = (short*)d_out;
    short* wb   = (short*)d_out + 4 * MB;
    short* PO0  = (short*)d_out;                   // [0,8M) after xb dies
    short* PO1  = (short*)d_out + 4 * MB;          // [8M,16M) after wb dies
    short* attn = PO1;                             // combine in-place
    float* out  = (float*)d_out;

    short* Qf = (short*)d_ws;
    short* Kf = Qf + (size_t)16 * 4096 * 64;
    short* Vf = Kf + (size_t)16 * 4096 * 64;       // [bh][64][4096]
    float* lbuf = (float*)((char*)d_ws + 24 * MB);
    short* pwb  = (short*)((char*)d_ws + 24 * MB + 512 * 1024);

    cvt3<<<2560, 256, 0, stream>>>(x, xb, 524288, qkv_w, wb, 98304, proj_w, pwb, 32768);
    qkv_gemm<<<dim3(64, 12), 256, 0, stream>>>(xb, wb, qkv_b, Qf, Kf, Vf);
    flash_attn<<<dim3(32, 16, 2), 256, 0, stream>>>(Qf, Kf, Vf, PO0, PO1, lbuf, 32);
    combine<<<2048, 256, 0, stream>>>((const short*)PO0, attn, lbuf);
    // proj A: rows [0,4096) -> d_out [0,8M)
    proj_piece<<<dim3(32, 4), 256, 0, stream>>>(attn, pwb, proj_b, out, 0);
    // proj B: rows [4096,6144) -> d_out [8M,12M) (reads attn [12M,14M))
    proj_piece<<<dim3(16, 4), 256, 0, stream>>>(attn, pwb, proj_b,
                                                (float*)((char*)d_out + 8 * MB), 4096);
    // proj C: rows [6144,8192) -> ws stage -> d_out [12M,16M)
    proj_piece<<<dim3(16, 4), 256, 0, stream>>>(attn, pwb, proj_b, (float*)d_ws, 6144);
    hipMemcpyAsync((char*)d_out + 12 * MB, d_ws, 4 * MB,
                   hipMemcpyDeviceToDevice, stream);
}

// Round 14
// 288.906 us; speedup vs baseline: 1.0636x; 1.0636x over previous
//
#include <hip/hip_runtime.h>
#include <hip/hip_bf16.h>
#include <stdint.h>
#include <stddef.h>

typedef __attribute__((ext_vector_type(8))) short short8;
typedef __attribute__((ext_vector_type(4))) float f32x4;

#define MFMA16(a, b, c) __builtin_amdgcn_mfma_f32_16x16x32_bf16((a), (b), (c), 0, 0, 0)

// Q pre-scale: HEAD_DIM^-0.5 * log2(e); flash uses raw v_exp_f32 (exp2)
#define QSCALE 0.1803368801111204f

#if __has_builtin(__builtin_amdgcn_exp2f)
#define EXP2(x) __builtin_amdgcn_exp2f(x)
#else
#define EXP2(x) __builtin_exp2f(x)
#endif

__device__ __forceinline__ float b2f(short x) {
    unsigned u = ((unsigned)(unsigned short)x) << 16;
    float f; __builtin_memcpy(&f, &u, 4); return f;
}
// round-nearest-even f32->bf16 (scalar)
__device__ __forceinline__ short f2b(float f) {
    unsigned u; __builtin_memcpy(&u, &f, 4);
    u = (u + 0x7FFFu + ((u >> 16) & 1u)) >> 16;
    return (short)u;
}
// two f32 -> packed bf16x2 in 3 VALU (2 adds + v_perm), round-half-up.
// (__float22bfloat162_rn is a multi-instr software sequence — r12 evidence.)
__device__ __forceinline__ unsigned pack2(float a, float b) {
    unsigned ua, ub; __builtin_memcpy(&ua, &a, 4); __builtin_memcpy(&ub, &b, 4);
    return __builtin_amdgcn_perm(ub + 0x8000u, ua + 0x8000u, 0x07060302u);
}
// 8 contiguous f32 -> bf16x8 (RNE)
__device__ __forceinline__ short8 load8f(const float* p) {
    const float4 f0 = *(const float4*)p;
    const float4 f1 = *(const float4*)(p + 4);
    short8 r;
    r[0]=f2b(f0.x); r[1]=f2b(f0.y); r[2]=f2b(f0.z); r[3]=f2b(f0.w);
    r[4]=f2b(f1.x); r[5]=f2b(f1.y); r[6]=f2b(f1.z); r[7]=f2b(f1.w);
    return r;
}

// ---------------------------------------------------------------------------
// Fused f32->bf16 converter for up to 3 arrays. nX = elems/8.
// ---------------------------------------------------------------------------
__global__ __launch_bounds__(256) void cvt3(
    const float* __restrict__ s0, short* __restrict__ d0, int n0,
    const float* __restrict__ s1, short* __restrict__ d1, int n1,
    const float* __restrict__ s2, short* __restrict__ d2, int n2)
{
    int i = blockIdx.x * 256 + threadIdx.x;
    if (i < n0) { *(short8*)(d0 + (size_t)i * 8) = load8f(s0 + (size_t)i * 8); return; }
    i -= n0;
    if (i < n1) { *(short8*)(d1 + (size_t)i * 8) = load8f(s1 + (size_t)i * 8); return; }
    i -= n1;
    if (i < n2) { *(short8*)(d2 + (size_t)i * 8) = load8f(s2 + (size_t)i * 8); }
}

// ---------------------------------------------------------------------------
// Fused QKV GEMM (bf16 in/out). Grid (64,12): sec = y>>2 (0=Q,1=K,2=V).
//   Q (x QSCALE) -> Qb[bh][seq][64];  K -> Kb[bh][seq][64]
//   V -> Vb[bh][64][seq] via LDS-transposed epilogue (coalesced b128 stores)
// ---------------------------------------------------------------------------
__global__ __launch_bounds__(256) void qkv_gemm(
    const short* __restrict__ X, const short* __restrict__ W,
    const float* __restrict__ bias,
    short* __restrict__ Qb, short* __restrict__ Kb, short* __restrict__ Vb)
{
    __shared__ short sT[128][132];

    const int tid  = threadIdx.x;
    const int wv   = tid >> 6;
    const int lane = tid & 63;
    const int l15  = lane & 15;
    const int quad = lane >> 4;
    const int m0   = blockIdx.x * 128 + (wv >> 1) * 64;
    const int sec  = blockIdx.y >> 2;
    const int bis  = blockIdx.y & 3;
    const int nbase = sec * 512 + bis * 128;
    const int j0   = (wv & 1) * 64;

    const f32x4 zero = {0.f, 0.f, 0.f, 0.f};
    f32x4 acc[4][4];
#pragma unroll
    for (int i = 0; i < 4; i++)
#pragma unroll
        for (int j = 0; j < 4; j++) acc[i][j] = zero;

    for (int k0 = 0; k0 < 512; k0 += 32) {
        short8 a[4], b[4];
#pragma unroll
        for (int i = 0; i < 4; i++)
            a[i] = *(const short8*)(X + (size_t)(m0 + i * 16 + l15) * 512 + k0 + quad * 8);
#pragma unroll
        for (int j = 0; j < 4; j++)
            b[j] = *(const short8*)(W + (size_t)(nbase + j0 + j * 16 + l15) * 512 + k0 + quad * 8);
#pragma unroll
        for (int i = 0; i < 4; i++)
#pragma unroll
            for (int j = 0; j < 4; j++)
                acc[i][j] = MFMA16(a[i], b[j], acc[i][j]);
    }

    if (sec < 2) {
        const float scale = (sec == 0) ? QSCALE : 1.0f;
        short* dst = (sec == 0) ? Qb : Kb;
#pragma unroll
        for (int j = 0; j < 4; j++) {
            const int jc = bis * 128 + j0 + j * 16 + l15;   // 0..511 in section
            const float bs = bias[sec * 512 + jc];
            const int hl = jc >> 6, d = jc & 63;
#pragma unroll
            for (int i = 0; i < 4; i++) {
#pragma unroll
                for (int r = 0; r < 4; r++) {
                    const int m = m0 + i * 16 + quad * 4 + r;
                    const int bb = m >> 12, seq = m & 4095;
                    dst[((size_t)(bb * 8 + hl) * 4096 + seq) * 64 + d] =
                        f2b((acc[i][j][r] + bs) * scale);
                }
            }
        }
    } else {
        // V: pack 4 consecutive seq into b64 LDS writes, then coalesced b128
#pragma unroll
        for (int j = 0; j < 4; j++) {
            const int jcl = j0 + j * 16 + l15;             // 0..127
            const float bs = bias[nbase + jcl];
#pragma unroll
            for (int i = 0; i < 4; i++) {
                uint2 w;
                w.x = pack2(acc[i][j][0] + bs, acc[i][j][1] + bs);
                w.y = pack2(acc[i][j][2] + bs, acc[i][j][3] + bs);
                *(uint2*)&sT[jcl][(wv >> 1) * 64 + i * 16 + quad * 4] = w;
            }
        }
        __syncthreads();

        const int jcl = tid >> 1, half = tid & 1;
        const int hl = (bis * 128 + jcl) >> 6;
        const int d  = jcl & 63;
        const int bb = (blockIdx.x * 128) >> 12;
        const int seq0 = ((blockIdx.x * 128) & 4095) + half * 64;
        short* dst = Vb + ((size_t)(bb * 8 + hl) * 64 + d) * 4096 + seq0;
#pragma unroll
        for (int u = 0; u < 8; u++)
            *(short8*)(dst + u * 8) = *(const short8*)&sT[jcl][half * 64 + u * 8];
    }
}

// ---------------------------------------------------------------------------
// Flash attention — r13 structure (grid (32,16,2), 4-wave blocks, 2 query-
// groups/wave, single wave-private sP, LDS 27.6 KB, EXP2 + pack2 VALU path,
// ones-MFMA row sums) + NEW: V fragments hoisted into registers once per
// tile (8 b128 reads) and reused across both groups — r13 re-read them per
// group (16 reads). DS-pipe issue model: 480 -> 384 cyc/wave-tile (-20%);
// flash is LDS-issue bound (r13 counters: DS model ~100us ~= dur 115us).
// Split-K=2 partials (no-max streaming softmax): O = (l0*O0+l1*O1)/(l0+l1).
// ---------------------------------------------------------------------------
__global__ __launch_bounds__(256) void flash_attn(
    const short* __restrict__ Q, const short* __restrict__ K,
    const short* __restrict__ V, short* __restrict__ PO0,
    short* __restrict__ PO1, float* __restrict__ lbuf, int ktiles)
{
    __shared__ short sK[64][72];
    __shared__ short sV[64][72];          // sV[d][key]
    __shared__ short sP[4][16][72];       // single per-wave buffer

    const int tid  = threadIdx.x;
    const int wv   = tid >> 6;
    const int lane = tid & 63;
    const int l15  = lane & 15;
    const int quad = lane >> 4;
    const int bh = blockIdx.y;
    const int b = bh >> 3, h = bh & 7;
    const int qw = blockIdx.x * 128 + wv * 32;   // wave's first query
    const int ks = blockIdx.z;
    const int key0 = ks * ktiles * 64;

    const short* Qb = Q + (size_t)bh * 4096 * 64;
    const short* Kb = K + (size_t)bh * 4096 * 64;
    const short* Vb = V + (size_t)bh * 64 * 4096;

    // Q fragments (B-operand): B[k=d][n=query l15]; Q pre-scaled by QSCALE
    const short8 aq00 = *(const short8*)(Qb + (size_t)(qw + l15) * 64 + quad * 8);
    const short8 aq01 = *(const short8*)(Qb + (size_t)(qw + l15) * 64 + 32 + quad * 8);
    const short8 aq10 = *(const short8*)(Qb + (size_t)(qw + 16 + l15) * 64 + quad * 8);
    const short8 aq11 = *(const short8*)(Qb + (size_t)(qw + 16 + l15) * 64 + 32 + quad * 8);

    const f32x4 zero = {0.f, 0.f, 0.f, 0.f};
    f32x4 o0[4], o1[4];
    f32x4 lac0 = zero, lac1 = zero;       // row sums via ones-MFMA
#pragma unroll
    for (int r = 0; r < 4; r++) { o0[r] = zero; o1[r] = zero; }
    const short one_bf = (short)0x3F80;
    const short8 ones = {one_bf, one_bf, one_bf, one_bf,
                         one_bf, one_bf, one_bf, one_bf};

    // staging: 1024 16B-chunks (K:512, V:512) over 256 threads -> 2+2 each
    int srow[2], scb[2];
#pragma unroll
    for (int i = 0; i < 2; i++) {
        const int c = tid + i * 256;
        srow[i] = c >> 3; scb[i] = (c & 7) * 8;
    }
    short8 pk[2], pv[2];
#pragma unroll
    for (int i = 0; i < 2; i++) {
        pk[i] = *(const short8*)(Kb + (size_t)(key0 + srow[i]) * 64 + scb[i]);
        pv[i] = *(const short8*)(Vb + (size_t)srow[i] * 4096 + key0 + scb[i]);
    }

    for (int kt = 0; kt < ktiles; ++kt) {
        const int k0 = key0 + kt * 64;
        __syncthreads();               // all waves done reading prev tile
#pragma unroll
        for (int i = 0; i < 2; i++) {
            *(short8*)&sK[srow[i]][scb[i]] = pk[i];
            *(short8*)&sV[srow[i]][scb[i]] = pv[i];
        }
        __syncthreads();               // staging visible

        if (kt + 1 < ktiles) {         // prefetch next tile (overlaps compute)
            const int k0n = k0 + 64;
#pragma unroll
            for (int i = 0; i < 2; i++) {
                pk[i] = *(const short8*)(Kb + (size_t)(k0n + srow[i]) * 64 + scb[i]);
                pv[i] = *(const short8*)(Vb + (size_t)srow[i] * 4096 + k0n + scb[i]);
            }
        }

        // S^T = K x Q^T for both groups (A=K[key][d] frags from LDS)
        f32x4 ST0[4], ST1[4];
#pragma unroll
        for (int c = 0; c < 4; c++) {
            const short8 bk0 = *(const short8*)&sK[c * 16 + l15][quad * 8];
            const short8 bk1 = *(const short8*)&sK[c * 16 + l15][32 + quad * 8];
            ST0[c] = MFMA16(bk1, aq01, MFMA16(bk0, aq00, zero));
            ST1[c] = MFMA16(bk1, aq11, MFMA16(bk0, aq10, zero));
        }

        // V fragments: load ONCE per tile, reuse across both groups (r14 new)
        short8 bv[4][2];
#pragma unroll
        for (int td = 0; td < 4; td++) {
            bv[td][0] = *(const short8*)&sV[td * 16 + l15][quad * 8];
            bv[td][1] = *(const short8*)&sV[td * 16 + l15][32 + quad * 8];
        }

        // ---- group 0 through the single sP buffer ----
#pragma unroll
        for (int c = 0; c < 4; c++) {
            uint2 w;
            w.x = pack2(EXP2(ST0[c][0]), EXP2(ST0[c][1]));
            w.y = pack2(EXP2(ST0[c][2]), EXP2(ST0[c][3]));
            *(uint2*)&sP[wv][l15][c * 16 + quad * 4] = w;
        }
        __threadfence_block();         // g0 writes -> g0 reads
        {
            const short8 bp0 = *(const short8*)&sP[wv][l15][quad * 8];
            const short8 bp1 = *(const short8*)&sP[wv][l15][32 + quad * 8];
            lac0 = MFMA16(ones, bp0, lac0);
            lac0 = MFMA16(ones, bp1, lac0);
#pragma unroll
            for (int td = 0; td < 4; td++) {
                o0[td] = MFMA16(bv[td][0], bp0, o0[td]);
                o0[td] = MFMA16(bv[td][1], bp1, o0[td]);
            }
        }
        __threadfence_block();         // g0 reads -> g1 writes

        // ---- group 1 ----
#pragma unroll
        for (int c = 0; c < 4; c++) {
            uint2 w;
            w.x = pack2(EXP2(ST1[c][0]), EXP2(ST1[c][1]));
            w.y = pack2(EXP2(ST1[c][2]), EXP2(ST1[c][3]));
            *(uint2*)&sP[wv][l15][c * 16 + quad * 4] = w;
        }
        __threadfence_block();         // g1 writes -> g1 reads
        {
            const short8 bp0 = *(const short8*)&sP[wv][l15][quad * 8];
            const short8 bp1 = *(const short8*)&sP[wv][l15][32 + quad * 8];
            lac1 = MFMA16(ones, bp0, lac1);
            lac1 = MFMA16(ones, bp1, lac1);
#pragma unroll
            for (int td = 0; td < 4; td++) {
                o1[td] = MFMA16(bv[td][0], bp0, o1[td]);
                o1[td] = MFMA16(bv[td][1], bp1, o1[td]);
            }
        }
        // g1 reads -> next-tile g0 writes ordered by the staging barrier
    }

    const float l0 = lac0[0];              // every reg/quad holds the sum
    const float l1 = lac1[0];
    const float inv0 = 1.f / fmaxf(l0, 1e-30f);
    const float inv1 = 1.f / fmaxf(l1, 1e-30f);

    short* PO = (ks == 0) ? PO0 : PO1;
#pragma unroll
    for (int td = 0; td < 4; td++) {
        uint2 w0, w1;
        w0.x = pack2(o0[td][0] * inv0, o0[td][1] * inv0);
        w0.y = pack2(o0[td][2] * inv0, o0[td][3] * inv0);
        w1.x = pack2(o1[td][0] * inv1, o1[td][1] * inv1);
        w1.y = pack2(o1[td][2] * inv1, o1[td][3] * inv1);
        const int col = h * 64 + td * 16 + quad * 4;
        *(uint2*)(PO + ((size_t)b * 4096 + qw + l15) * 512 + col) = w0;
        *(uint2*)(PO + ((size_t)b * 4096 + qw + 16 + l15) * 512 + col) = w1;
    }
    if (quad == 0) {
        lbuf[((size_t)ks * 16 + bh) * 4096 + qw + l15] = l0;
        lbuf[((size_t)ks * 16 + bh) * 4096 + qw + 16 + l15] = l1;
    }
}

// ---------------------------------------------------------------------------
// Combine the 2 key-split partials (in-place over PO1 = attn region):
// attn = (l0*O0 + l1*O1) / (l0+l1). Element-wise, memory-bound.
// ---------------------------------------------------------------------------
__global__ __launch_bounds__(256) void combine(
    const short* __restrict__ PO0, short* __restrict__ PO1,
    const float* __restrict__ L)
{
    const int i = blockIdx.x * 256 + threadIdx.x;   // 0..524287
    const size_t flat = (size_t)i * 8;
    const int col = (int)(flat & 511);
    const int q   = (int)((flat >> 9) & 4095);
    const int b   = (int)(flat >> 21);
    const int bh  = b * 8 + (col >> 6);
    const float l0 = L[(size_t)bh * 4096 + q];
    const float l1 = L[(size_t)65536 + (size_t)bh * 4096 + q];
    const float inv = 1.f / (l0 + l1);
    const float w0 = l0 * inv, w1 = l1 * inv;
    const short8 a = *(const short8*)(PO0 + flat);
    const short8 c = *(const short8*)(PO1 + flat);
    short8 r;
#pragma unroll
    for (int k = 0; k < 8; k += 2) {
        const unsigned p = pack2(w0 * b2f(a[k]) + w1 * b2f(c[k]),
                                 w0 * b2f(a[k + 1]) + w1 * b2f(c[k + 1]));
        r[k]     = (short)(p & 0xFFFF);
        r[k + 1] = (short)(p >> 16);
    }
    *(short8*)(PO1 + flat) = r;
}

// ---------------------------------------------------------------------------
// Projection piece: dst[m_local][n] = attn[m_base+m_local] @ pw^T + proj_b.
// attn bf16, pw bf16, bias f32, dst f32. Grid (rows/128, 4).
// ---------------------------------------------------------------------------
__global__ __launch_bounds__(256) void proj_piece(
    const short* __restrict__ A, const short* __restrict__ W,
    const float* __restrict__ bias, float* __restrict__ dst, int m_base)
{
    const int tid  = threadIdx.x;
    const int wv   = tid >> 6;
    const int lane = tid & 63;
    const int l15  = lane & 15;
    const int quad = lane >> 4;
    const int m0 = blockIdx.x * 128 + (wv >> 1) * 64;
    const int n0 = blockIdx.y * 128 + (wv & 1) * 64;

    const f32x4 zero = {0.f, 0.f, 0.f, 0.f};
    f32x4 acc[4][4];
#pragma unroll
    for (int i = 0; i < 4; i++)
#pragma unroll
        for (int j = 0; j < 4; j++) acc[i][j] = zero;

    for (int k0 = 0; k0 < 512; k0 += 32) {
        short8 a[4], b[4];
#pragma unroll
        for (int i = 0; i < 4; i++)
            a[i] = *(const short8*)(A + (size_t)(m_base + m0 + i * 16 + l15) * 512 + k0 + quad * 8);
#pragma unroll
        for (int j = 0; j < 4; j++)
            b[j] = *(const short8*)(W + (size_t)(n0 + j * 16 + l15) * 512 + k0 + quad * 8);
#pragma unroll
        for (int i = 0; i < 4; i++)
#pragma unroll
            for (int j = 0; j < 4; j++)
                acc[i][j] = MFMA16(a[i], b[j], acc[i][j]);
    }

#pragma unroll
    for (int j = 0; j < 4; j++) {
        const int n = n0 + j * 16 + l15;
        const float bs = bias[n];
#pragma unroll
        for (int i = 0; i < 4; i++) {
#pragma unroll
            for (int r = 0; r < 4; r++) {
                const int m = m0 + i * 16 + quad * 4 + r;
                dst[(size_t)m * 512 + n] = acc[i][j][r] + bs;
            }
        }
    }
}

// ---------------------------------------------------------------------------
// Memory plan (ws >= 25 MB, proven; proj tail = r10's proven 2-piece form):
//   d_out [0,8M):    xb -> PO0 (flash split 0) -> proj A output (direct)
//   d_out [8M,9.5M): wb (dead after qkv)
//   d_out [8M,16M):  PO1 (flash split 1) -> combine in-place -> attn
//   proj A rows [0,4096) -> d_out [0,8M) direct (reads attn [8M,16M));
//   proj B rows [4096,8192) -> ws [0,8M) stage (Qf dead) -> copy to [8M,16M).
//   ws [0,8M) Qf | [8M,16M) Kf | [16M,24M) Vf | [24M,24.5M) lbuf | pwb
// ---------------------------------------------------------------------------
extern "C" void kernel_launch(void* const* d_in, const int* in_sizes, int n_in,
                              void* d_out, int out_size, void* d_ws, size_t ws_size,
                              hipStream_t stream)
{
    const float* x      = (const float*)d_in[0];   // [2,4096,512] f32
    const float* qkv_w  = (const float*)d_in[1];   // [1536,512]   f32
    const float* qkv_b  = (const float*)d_in[2];   // [1536]       f32
    const float* proj_w = (const float*)d_in[3];   // [512,512]    f32
    const float* proj_b = (const float*)d_in[4];   // [512]        f32

    const size_t MB = 1024 * 1024;
    short* xb   = (short*)d_out;
    short* wb   = (short*)d_out + 4 * MB;
    short* PO0  = (short*)d_out;                   // [0,8M) after xb dies
    short* PO1  = (short*)d_out + 4 * MB;          // [8M,16M) after wb dies
    short* attn = PO1;                             // combine in-place
    float* out  = (float*)d_out;

    short* Qf = (short*)d_ws;
    short* Kf = Qf + (size_t)16 * 4096 * 64;
    short* Vf = Kf + (size_t)16 * 4096 * 64;       // [bh][64][4096]
    float* lbuf = (float*)((char*)d_ws + 24 * MB);
    short* pwb  = (short*)((char*)d_ws + 24 * MB + 512 * 1024);

    cvt3<<<2560, 256, 0, stream>>>(x, xb, 524288, qkv_w, wb, 98304, proj_w, pwb, 32768);
    qkv_gemm<<<dim3(64, 12), 256, 0, stream>>>(xb, wb, qkv_b, Qf, Kf, Vf);
    flash_attn<<<dim3(32, 16, 2), 256, 0, stream>>>(Qf, Kf, Vf, PO0, PO1, lbuf, 32);
    combine<<<2048, 256, 0, stream>>>((const short*)PO0, attn, lbuf);
    // proj A: rows [0,4096) -> d_out [0,8M) direct (reads attn [8M,16M))
    proj_piece<<<dim3(32, 4), 256, 0, stream>>>(attn, pwb, proj_b, out, 0);
    // proj B: rows [4096,8192) -> ws stage (Qf dead) -> copy over attn region
    proj_piece<<<dim3(32, 4), 256, 0, stream>>>(attn, pwb, proj_b, (float*)d_ws, 4096);
    hipMemcpyAsync((char*)d_out + 8 * MB, d_ws, 8 * MB,
                   hipMemcpyDeviceToDevice, stream);
}

// Round 15
// 264.415 us; speedup vs baseline: 1.1621x; 1.0926x over previous
//
#include <hip/hip_runtime.h>
#include <hip/hip_bf16.h>
#include <stdint.h>
#include <stddef.h>

typedef __attribute__((ext_vector_type(8))) short short8;
typedef __attribute__((ext_vector_type(4))) float f32x4;

#define MFMA16(a, b, c) __builtin_amdgcn_mfma_f32_16x16x32_bf16((a), (b), (c), 0, 0, 0)

// Q pre-scale: HEAD_DIM^-0.5 * log2(e); flash uses raw v_exp_f32 (exp2)
#define QSCALE 0.1803368801111204f

#if __has_builtin(__builtin_amdgcn_exp2f)
#define EXP2(x) __builtin_amdgcn_exp2f(x)
#else
#define EXP2(x) __builtin_exp2f(x)
#endif

__device__ __forceinline__ float b2f(short x) {
    unsigned u = ((unsigned)(unsigned short)x) << 16;
    float f; __builtin_memcpy(&f, &u, 4); return f;
}
// round-nearest-even f32->bf16 (scalar)
__device__ __forceinline__ short f2b(float f) {
    unsigned u; __builtin_memcpy(&u, &f, 4);
    u = (u + 0x7FFFu + ((u >> 16) & 1u)) >> 16;
    return (short)u;
}
// two f32 -> packed bf16x2 in 3 VALU (2 adds + v_perm), round-half-up.
// (__float22bfloat162_rn is a multi-instr software sequence — r12 evidence.)
__device__ __forceinline__ unsigned pack2(float a, float b) {
    unsigned ua, ub; __builtin_memcpy(&ua, &a, 4); __builtin_memcpy(&ub, &b, 4);
    return __builtin_amdgcn_perm(ub + 0x8000u, ua + 0x8000u, 0x07060302u);
}
// 8 contiguous f32 -> bf16x8 (RNE)
__device__ __forceinline__ short8 load8f(const float* p) {
    const float4 f0 = *(const float4*)p;
    const float4 f1 = *(const float4*)(p + 4);
    short8 r;
    r[0]=f2b(f0.x); r[1]=f2b(f0.y); r[2]=f2b(f0.z); r[3]=f2b(f0.w);
    r[4]=f2b(f1.x); r[5]=f2b(f1.y); r[6]=f2b(f1.z); r[7]=f2b(f1.w);
    return r;
}

// ---------------------------------------------------------------------------
// Fused f32->bf16 converter for up to 3 arrays. nX = elems/8.
// ---------------------------------------------------------------------------
__global__ __launch_bounds__(256) void cvt3(
    const float* __restrict__ s0, short* __restrict__ d0, int n0,
    const float* __restrict__ s1, short* __restrict__ d1, int n1,
    const float* __restrict__ s2, short* __restrict__ d2, int n2)
{
    int i = blockIdx.x * 256 + threadIdx.x;
    if (i < n0) { *(short8*)(d0 + (size_t)i * 8) = load8f(s0 + (size_t)i * 8); return; }
    i -= n0;
    if (i < n1) { *(short8*)(d1 + (size_t)i * 8) = load8f(s1 + (size_t)i * 8); return; }
    i -= n1;
    if (i < n2) { *(short8*)(d2 + (size_t)i * 8) = load8f(s2 + (size_t)i * 8); }
}

// ---------------------------------------------------------------------------
// Fused QKV GEMM (bf16 in/out). Grid (64,12): sec = y>>2 (0=Q,1=K,2=V).
//   Q (x QSCALE) -> Qb[bh][seq][64];  K -> Kb[bh][seq][64]
//   V -> Vb[bh][64][seq] via LDS-transposed epilogue (coalesced b128 stores)
// ---------------------------------------------------------------------------
__global__ __launch_bounds__(256) void qkv_gemm(
    const short* __restrict__ X, const short* __restrict__ W,
    const float* __restrict__ bias,
    short* __restrict__ Qb, short* __restrict__ Kb, short* __restrict__ Vb)
{
    __shared__ short sT[128][132];

    const int tid  = threadIdx.x;
    const int wv   = tid >> 6;
    const int lane = tid & 63;
    const int l15  = lane & 15;
    const int quad = lane >> 4;
    const int m0   = blockIdx.x * 128 + (wv >> 1) * 64;
    const int sec  = blockIdx.y >> 2;
    const int bis  = blockIdx.y & 3;
    const int nbase = sec * 512 + bis * 128;
    const int j0   = (wv & 1) * 64;

    const f32x4 zero = {0.f, 0.f, 0.f, 0.f};
    f32x4 acc[4][4];
#pragma unroll
    for (int i = 0; i < 4; i++)
#pragma unroll
        for (int j = 0; j < 4; j++) acc[i][j] = zero;

    for (int k0 = 0; k0 < 512; k0 += 32) {
        short8 a[4], b[4];
#pragma unroll
        for (int i = 0; i < 4; i++)
            a[i] = *(const short8*)(X + (size_t)(m0 + i * 16 + l15) * 512 + k0 + quad * 8);
#pragma unroll
        for (int j = 0; j < 4; j++)
            b[j] = *(const short8*)(W + (size_t)(nbase + j0 + j * 16 + l15) * 512 + k0 + quad * 8);
#pragma unroll
        for (int i = 0; i < 4; i++)
#pragma unroll
            for (int j = 0; j < 4; j++)
                acc[i][j] = MFMA16(a[i], b[j], acc[i][j]);
    }

    if (sec < 2) {
        const float scale = (sec == 0) ? QSCALE : 1.0f;
        short* dst = (sec == 0) ? Qb : Kb;
#pragma unroll
        for (int j = 0; j < 4; j++) {
            const int jc = bis * 128 + j0 + j * 16 + l15;   // 0..511 in section
            const float bs = bias[sec * 512 + jc];
            const int hl = jc >> 6, d = jc & 63;
#pragma unroll
            for (int i = 0; i < 4; i++) {
#pragma unroll
                for (int r = 0; r < 4; r++) {
                    const int m = m0 + i * 16 + quad * 4 + r;
                    const int bb = m >> 12, seq = m & 4095;
                    dst[((size_t)(bb * 8 + hl) * 4096 + seq) * 64 + d] =
                        f2b((acc[i][j][r] + bs) * scale);
                }
            }
        }
    } else {
        // V: pack 4 consecutive seq into b64 LDS writes, then coalesced b128
#pragma unroll
        for (int j = 0; j < 4; j++) {
            const int jcl = j0 + j * 16 + l15;             // 0..127
            const float bs = bias[nbase + jcl];
#pragma unroll
            for (int i = 0; i < 4; i++) {
                uint2 w;
                w.x = pack2(acc[i][j][0] + bs, acc[i][j][1] + bs);
                w.y = pack2(acc[i][j][2] + bs, acc[i][j][3] + bs);
                *(uint2*)&sT[jcl][(wv >> 1) * 64 + i * 16 + quad * 4] = w;
            }
        }
        __syncthreads();

        const int jcl = tid >> 1, half = tid & 1;
        const int hl = (bis * 128 + jcl) >> 6;
        const int d  = jcl & 63;
        const int bb = (blockIdx.x * 128) >> 12;
        const int seq0 = ((blockIdx.x * 128) & 4095) + half * 64;
        short* dst = Vb + ((size_t)(bb * 8 + hl) * 64 + d) * 4096 + seq0;
#pragma unroll
        for (int u = 0; u < 8; u++)
            *(short8*)(dst + u * 8) = *(const short8*)&sT[jcl][half * 64 + u * 8];
    }
}

// ---------------------------------------------------------------------------
// Flash attention — UNCHANGED from r14 (114.6 us): grid (32,16,2), 4-wave
// blocks, 2 query-groups/wave, single wave-private sP (LDS 27.6 KB), EXP2 +
// pack2 VALU path, ones-MFMA row sums, V-frags hoisted per tile.
// r13/r14 lesson: VALU -24pts and DS-traffic -22% both left dur at ~115 —
// flash is combined-issue-port bound; next lever = fewer instructions
// (32x32x16 MFMA), not pipe rebalancing.
// Split-K=2 partials (no-max streaming softmax): O = (l0*O0+l1*O1)/(l0+l1).
// ---------------------------------------------------------------------------
__global__ __launch_bounds__(256) void flash_attn(
    const short* __restrict__ Q, const short* __restrict__ K,
    const short* __restrict__ V, short* __restrict__ PO0,
    short* __restrict__ PO1, float* __restrict__ lbuf, int ktiles)
{
    __shared__ short sK[64][72];
    __shared__ short sV[64][72];          // sV[d][key]
    __shared__ short sP[4][16][72];       // single per-wave buffer

    const int tid  = threadIdx.x;
    const int wv   = tid >> 6;
    const int lane = tid & 63;
    const int l15  = lane & 15;
    const int quad = lane >> 4;
    const int bh = blockIdx.y;
    const int b = bh >> 3, h = bh & 7;
    const int qw = blockIdx.x * 128 + wv * 32;   // wave's first query
    const int ks = blockIdx.z;
    const int key0 = ks * ktiles * 64;

    const short* Qb = Q + (size_t)bh * 4096 * 64;
    const short* Kb = K + (size_t)bh * 4096 * 64;
    const short* Vb = V + (size_t)bh * 64 * 4096;

    // Q fragments (B-operand): B[k=d][n=query l15]; Q pre-scaled by QSCALE
    const short8 aq00 = *(const short8*)(Qb + (size_t)(qw + l15) * 64 + quad * 8);
    const short8 aq01 = *(const short8*)(Qb + (size_t)(qw + l15) * 64 + 32 + quad * 8);
    const short8 aq10 = *(const short8*)(Qb + (size_t)(qw + 16 + l15) * 64 + quad * 8);
    const short8 aq11 = *(const short8*)(Qb + (size_t)(qw + 16 + l15) * 64 + 32 + quad * 8);

    const f32x4 zero = {0.f, 0.f, 0.f, 0.f};
    f32x4 o0[4], o1[4];
    f32x4 lac0 = zero, lac1 = zero;       // row sums via ones-MFMA
#pragma unroll
    for (int r = 0; r < 4; r++) { o0[r] = zero; o1[r] = zero; }
    const short one_bf = (short)0x3F80;
    const short8 ones = {one_bf, one_bf, one_bf, one_bf,
                         one_bf, one_bf, one_bf, one_bf};

    // staging: 1024 16B-chunks (K:512, V:512) over 256 threads -> 2+2 each
    int srow[2], scb[2];
#pragma unroll
    for (int i = 0; i < 2; i++) {
        const int c = tid + i * 256;
        srow[i] = c >> 3; scb[i] = (c & 7) * 8;
    }
    short8 pk[2], pv[2];
#pragma unroll
    for (int i = 0; i < 2; i++) {
        pk[i] = *(const short8*)(Kb + (size_t)(key0 + srow[i]) * 64 + scb[i]);
        pv[i] = *(const short8*)(Vb + (size_t)srow[i] * 4096 + key0 + scb[i]);
    }

    for (int kt = 0; kt < ktiles; ++kt) {
        const int k0 = key0 + kt * 64;
        __syncthreads();               // all waves done reading prev tile
#pragma unroll
        for (int i = 0; i < 2; i++) {
            *(short8*)&sK[srow[i]][scb[i]] = pk[i];
            *(short8*)&sV[srow[i]][scb[i]] = pv[i];
        }
        __syncthreads();               // staging visible

        if (kt + 1 < ktiles) {         // prefetch next tile (overlaps compute)
            const int k0n = k0 + 64;
#pragma unroll
            for (int i = 0; i < 2; i++) {
                pk[i] = *(const short8*)(Kb + (size_t)(k0n + srow[i]) * 64 + scb[i]);
                pv[i] = *(const short8*)(Vb + (size_t)srow[i] * 4096 + k0n + scb[i]);
            }
        }

        // S^T = K x Q^T for both groups (A=K[key][d] frags from LDS)
        f32x4 ST0[4], ST1[4];
#pragma unroll
        for (int c = 0; c < 4; c++) {
            const short8 bk0 = *(const short8*)&sK[c * 16 + l15][quad * 8];
            const short8 bk1 = *(const short8*)&sK[c * 16 + l15][32 + quad * 8];
            ST0[c] = MFMA16(bk1, aq01, MFMA16(bk0, aq00, zero));
            ST1[c] = MFMA16(bk1, aq11, MFMA16(bk0, aq10, zero));
        }

        // V fragments: load ONCE per tile, reuse across both groups
        short8 bv[4][2];
#pragma unroll
        for (int td = 0; td < 4; td++) {
            bv[td][0] = *(const short8*)&sV[td * 16 + l15][quad * 8];
            bv[td][1] = *(const short8*)&sV[td * 16 + l15][32 + quad * 8];
        }

        // ---- group 0 through the single sP buffer ----
#pragma unroll
        for (int c = 0; c < 4; c++) {
            uint2 w;
            w.x = pack2(EXP2(ST0[c][0]), EXP2(ST0[c][1]));
            w.y = pack2(EXP2(ST0[c][2]), EXP2(ST0[c][3]));
            *(uint2*)&sP[wv][l15][c * 16 + quad * 4] = w;
        }
        __threadfence_block();         // g0 writes -> g0 reads
        {
            const short8 bp0 = *(const short8*)&sP[wv][l15][quad * 8];
            const short8 bp1 = *(const short8*)&sP[wv][l15][32 + quad * 8];
            lac0 = MFMA16(ones, bp0, lac0);
            lac0 = MFMA16(ones, bp1, lac0);
#pragma unroll
            for (int td = 0; td < 4; td++) {
                o0[td] = MFMA16(bv[td][0], bp0, o0[td]);
                o0[td] = MFMA16(bv[td][1], bp1, o0[td]);
            }
        }
        __threadfence_block();         // g0 reads -> g1 writes

        // ---- group 1 ----
#pragma unroll
        for (int c = 0; c < 4; c++) {
            uint2 w;
            w.x = pack2(EXP2(ST1[c][0]), EXP2(ST1[c][1]));
            w.y = pack2(EXP2(ST1[c][2]), EXP2(ST1[c][3]));
            *(uint2*)&sP[wv][l15][c * 16 + quad * 4] = w;
        }
        __threadfence_block();         // g1 writes -> g1 reads
        {
            const short8 bp0 = *(const short8*)&sP[wv][l15][quad * 8];
            const short8 bp1 = *(const short8*)&sP[wv][l15][32 + quad * 8];
            lac1 = MFMA16(ones, bp0, lac1);
            lac1 = MFMA16(ones, bp1, lac1);
#pragma unroll
            for (int td = 0; td < 4; td++) {
                o1[td] = MFMA16(bv[td][0], bp0, o1[td]);
                o1[td] = MFMA16(bv[td][1], bp1, o1[td]);
            }
        }
        // g1 reads -> next-tile g0 writes ordered by the staging barrier
    }

    const float l0 = lac0[0];              // every reg/quad holds the sum
    const float l1 = lac1[0];
    const float inv0 = 1.f / fmaxf(l0, 1e-30f);
    const float inv1 = 1.f / fmaxf(l1, 1e-30f);

    short* PO = (ks == 0) ? PO0 : PO1;
#pragma unroll
    for (int td = 0; td < 4; td++) {
        uint2 w0, w1;
        w0.x = pack2(o0[td][0] * inv0, o0[td][1] * inv0);
        w0.y = pack2(o0[td][2] * inv0, o0[td][3] * inv0);
        w1.x = pack2(o1[td][0] * inv1, o1[td][1] * inv1);
        w1.y = pack2(o1[td][2] * inv1, o1[td][3] * inv1);
        const int col = h * 64 + td * 16 + quad * 4;
        *(uint2*)(PO + ((size_t)b * 4096 + qw + l15) * 512 + col) = w0;
        *(uint2*)(PO + ((size_t)b * 4096 + qw + 16 + l15) * 512 + col) = w1;
    }
    if (quad == 0) {
        lbuf[((size_t)ks * 16 + bh) * 4096 + qw + l15] = l0;
        lbuf[((size_t)ks * 16 + bh) * 4096 + qw + 16 + l15] = l1;
    }
}

// ---------------------------------------------------------------------------
// Combine the 2 key-split partials: attn(ws) = (l0*O0 + l1*O1)/(l0+l1).
// Writes to ws (Qf region, dead after flash) so proj can write d_out
// directly with no hazard. Element-wise, memory-bound.
// ---------------------------------------------------------------------------
__global__ __launch_bounds__(256) void combine(
    const short* __restrict__ PO0, const short* __restrict__ PO1,
    short* __restrict__ attn, const float* __restrict__ L)
{
    const int i = blockIdx.x * 256 + threadIdx.x;   // 0..524287
    const size_t flat = (size_t)i * 8;
    const int col = (int)(flat & 511);
    const int q   = (int)((flat >> 9) & 4095);
    const int b   = (int)(flat >> 21);
    const int bh  = b * 8 + (col >> 6);
    const float l0 = L[(size_t)bh * 4096 + q];
    const float l1 = L[(size_t)65536 + (size_t)bh * 4096 + q];
    const float inv = 1.f / (l0 + l1);
    const float w0 = l0 * inv, w1 = l1 * inv;
    const short8 a = *(const short8*)(PO0 + flat);
    const short8 c = *(const short8*)(PO1 + flat);
    short8 r;
#pragma unroll
    for (int k = 0; k < 8; k += 2) {
        const unsigned p = pack2(w0 * b2f(a[k]) + w1 * b2f(c[k]),
                                 w0 * b2f(a[k + 1]) + w1 * b2f(c[k + 1]));
        r[k]     = (short)(p & 0xFFFF);
        r[k + 1] = (short)(p >> 16);
    }
    *(short8*)(attn + flat) = r;
}

// ---------------------------------------------------------------------------
// Projection, SINGLE full-GPU launch: grid (64,4) = 256 blocks (r14 ran two
// serialized 128-block pieces = half-GPU each). dst = d_out f32 direct
// (A comes from ws-attn, so no read/write hazard, no stage, no copy).
// ---------------------------------------------------------------------------
__global__ __launch_bounds__(256) void proj_gemm(
    const short* __restrict__ A, const short* __restrict__ W,
    const float* __restrict__ bias, float* __restrict__ dst)
{
    const int tid  = threadIdx.x;
    const int wv   = tid >> 6;
    const int lane = tid & 63;
    const int l15  = lane & 15;
    const int quad = lane >> 4;
    const int m0 = blockIdx.x * 128 + (wv >> 1) * 64;   // 0..8191
    const int n0 = blockIdx.y * 128 + (wv & 1) * 64;

    const f32x4 zero = {0.f, 0.f, 0.f, 0.f};
    f32x4 acc[4][4];
#pragma unroll
    for (int i = 0; i < 4; i++)
#pragma unroll
        for (int j = 0; j < 4; j++) acc[i][j] = zero;

    for (int k0 = 0; k0 < 512; k0 += 32) {
        short8 a[4], b[4];
#pragma unroll
        for (int i = 0; i < 4; i++)
            a[i] = *(const short8*)(A + (size_t)(m0 + i * 16 + l15) * 512 + k0 + quad * 8);
#pragma unroll
        for (int j = 0; j < 4; j++)
            b[j] = *(const short8*)(W + (size_t)(n0 + j * 16 + l15) * 512 + k0 + quad * 8);
#pragma unroll
        for (int i = 0; i < 4; i++)
#pragma unroll
            for (int j = 0; j < 4; j++)
                acc[i][j] = MFMA16(a[i], b[j], acc[i][j]);
    }

#pragma unroll
    for (int j = 0; j < 4; j++) {
        const int n = n0 + j * 16 + l15;
        const float bs = bias[n];
#pragma unroll
        for (int i = 0; i < 4; i++) {
#pragma unroll
            for (int r = 0; r < 4; r++) {
                const int m = m0 + i * 16 + quad * 4 + r;
                dst[(size_t)m * 512 + n] = acc[i][j][r] + bs;
            }
        }
    }
}

// ---------------------------------------------------------------------------
// Memory plan (ws >= 25 MB, proven). 5 dispatches (was 7 — r14 rest=174us
// vs ~80us bottom-up model suggests ~10us/dispatch gaps; this round tests it):
//   d_out [0,8M):    xb -> PO0 (flash split 0) -> proj output [0,8M)
//   d_out [8M,9.5M): wb (dead after qkv)
//   d_out [8M,16M):  PO1 (flash split 1) -> proj output [8M,16M)
//   ws [0,8M):  Qf -> attn (combine output; Qf dead after flash)
//   ws [8M,16M) Kf | [16M,24M) Vf | [24M,24.5M) lbuf | [24.5M,25M) pwb
// ---------------------------------------------------------------------------
extern "C" void kernel_launch(void* const* d_in, const int* in_sizes, int n_in,
                              void* d_out, int out_size, void* d_ws, size_t ws_size,
                              hipStream_t stream)
{
    const float* x      = (const float*)d_in[0];   // [2,4096,512] f32
    const float* qkv_w  = (const float*)d_in[1];   // [1536,512]   f32
    const float* qkv_b  = (const float*)d_in[2];   // [1536]       f32
    const float* proj_w = (const float*)d_in[3];   // [512,512]    f32
    const float* proj_b = (const float*)d_in[4];   // [512]        f32

    const size_t MB = 1024 * 1024;
    short* xb   = (short*)d_out;
    short* wb   = (short*)d_out + 4 * MB;
    short* PO0  = (short*)d_out;                   // [0,8M) after xb dies
    short* PO1  = (short*)d_out + 4 * MB;          // [8M,16M) after wb dies
    float* out  = (float*)d_out;

    short* Qf = (short*)d_ws;
    short* Kf = Qf + (size_t)16 * 4096 * 64;
    short* Vf = Kf + (size_t)16 * 4096 * 64;       // [bh][64][4096]
    short* attn = Qf;                              // ws [0,8M), post-flash life
    float* lbuf = (float*)((char*)d_ws + 24 * MB);
    short* pwb  = (short*)((char*)d_ws + 24 * MB + 512 * 1024);

    cvt3<<<2560, 256, 0, stream>>>(x, xb, 524288, qkv_w, wb, 98304, proj_w, pwb, 32768);
    qkv_gemm<<<dim3(64, 12), 256, 0, stream>>>(xb, wb, qkv_b, Qf, Kf, Vf);
    flash_attn<<<dim3(32, 16, 2), 256, 0, stream>>>(Qf, Kf, Vf, PO0, PO1, lbuf, 32);
    combine<<<2048, 256, 0, stream>>>(PO0, PO1, attn, lbuf);
    proj_gemm<<<dim3(64, 4), 256, 0, stream>>>(attn, pwb, proj_b, out);
}